// Round 2
// baseline (220.260 us; speedup 1.0000x reference)
//
#include <hip/hip_runtime.h>

#define B 4096
#define D 16
#define R 1024
#define NC 10
#define IC 170      // 17*10
#define ICP 192     // padded leading dim for LDS C2 tile
#define RC 64       // rules per K-chunk in GEMM
#define BT 16       // batch rows per GEMM block

// ---------------- K0: pack rule_idx (16 dims x 2 bits) into one u32 per rule
__global__ void pack_rules(const int* __restrict__ rule_idx, unsigned* __restrict__ packed) {
    int r = blockIdx.x * 256 + threadIdx.x;
    unsigned bits = 0;
#pragma unroll
    for (int d = 0; d < D; ++d)
        bits |= (((unsigned)rule_idx[d * R + r]) & 3u) << (2 * d);
    packed[r] = bits;
}

// ---------------- K1: firing strengths + normalization + x_ext
__global__ __launch_bounds__(256) void firing_kernel(
    const float* __restrict__ x, const float* __restrict__ centers,
    const float* __restrict__ widths, const unsigned* __restrict__ packed,
    float* __restrict__ out_norm, float* __restrict__ out_xext)
{
    __shared__ float s_z[64];
    __shared__ float s_red[8];
    const int b = blockIdx.x, tid = threadIdx.x;

    if (tid < 64) {
        int d = tid >> 2;
        float xv = x[b * D + d];
        float c  = centers[tid];
        float w  = widths[tid];
        float diff = xv - c;
        // log of mf: -(x-c)^2/(2 w^2) + 1e-9  (the 1e-9 is inside the exp in the ref)
        s_z[tid] = 1e-9f - diff * diff / (2.0f * w * w);
    }
    if (tid < 17) out_xext[b * 17 + tid] = (tid < 16) ? x[b * D + tid] : 1.0f;
    __syncthreads();

    float f[4];
    float lsum = 0.0f;
#pragma unroll
    for (int j = 0; j < 4; ++j) {
        int r = tid + 256 * j;
        unsigned bits = packed[r];
        float s = 0.0f;
#pragma unroll
        for (int d = 0; d < D; ++d)
            s += s_z[(d << 2) | ((bits >> (2 * d)) & 3u)];
        f[j] = __expf(s);
        lsum += f[j];
    }
    // wave64 butterfly reduce, then cross-wave via LDS
#pragma unroll
    for (int off = 1; off < 64; off <<= 1) lsum += __shfl_xor(lsum, off, 64);
    const int lane = tid & 63, wid = tid >> 6;
    if (lane == 0) s_red[wid] = lsum;
    __syncthreads();
    if (tid == 0) {
        float tot = s_red[0] + s_red[1] + s_red[2] + s_red[3] + 1e-9f;
        s_red[4] = 1.0f / tot;
    }
    __syncthreads();
    const float inv = s_red[4];
#pragma unroll
    for (int j = 0; j < 4; ++j)
        out_norm[(size_t)b * R + tid + 256 * j] = f[j] * inv;
}

// ---------------- K2: y_hat[b,c] = sum_i x_ext[b,i] * (sum_r norm_fs[b,r]*C2[r,i*10+c])
// Block: BT=16 batch rows, full 170 (pad 192) "ic" columns, K-loop over 1024 rules.
// Wave layout: 4 batch rows x 16 ic-groups -> ds_read_b128 sees only 16 unique
// addresses (broadcast across the 4 row-groups).
__global__ __launch_bounds__(256) void yhat_kernel(
    const float* __restrict__ norm, const float* __restrict__ cons,
    const float* __restrict__ x, float* __restrict__ out_y)
{
    __shared__ float c2s[RC * ICP];   // 64*192*4 = 48 KiB (reused as G in epilogue)
    __shared__ float wsh[BT * RC];    // 4 KiB
    __shared__ float xe[BT * 17];

    const int tid = threadIdx.x;
    const int bl0 = blockIdx.x * BT;

    // BT*17 = 272 > 256: MUST be a strided loop (round-1 bug: row 15 garbage)
    for (int t = tid; t < BT * 17; t += 256) {
        int bl = t / 17, i = t % 17;
        xe[t] = (i < 16) ? x[(size_t)(bl0 + bl) * D + i] : 1.0f;
    }

    const int lane = tid & 63, wvid = tid >> 6;
    const int icg = lane & 15;
    const int bl_local = wvid * 4 + (lane >> 4);

    float acc[3][4];
#pragma unroll
    for (int p = 0; p < 3; ++p)
#pragma unroll
        for (int q = 0; q < 4; ++q) acc[p][q] = 0.0f;

    for (int r0 = 0; r0 < R; r0 += RC) {
        __syncthreads();
        // stage C2 chunk (RC x 170 floats) as float2 into padded LDS rows
        for (int t = tid; t < RC * 85; t += 256) {
            int rr = t / 85;
            int j2 = (t - rr * 85) * 2;
            float2 v = *(const float2*)(cons + (size_t)(r0 + rr) * IC + j2);
            *(float2*)&c2s[rr * ICP + j2] = v;
        }
        // stage norm_fs tile (BT x RC), coalesced along rules
#pragma unroll
        for (int s = 0; s < 4; ++s) {
            int t = tid + 256 * s;
            wsh[t] = norm[(size_t)(bl0 + (t >> 6)) * R + r0 + (t & 63)];
        }
        __syncthreads();

        for (int rr4 = 0; rr4 < RC; rr4 += 4) {
            float4 wv4 = *(const float4*)&wsh[bl_local * RC + rr4];
            float wq[4] = {wv4.x, wv4.y, wv4.z, wv4.w};
#pragma unroll
            for (int k = 0; k < 4; ++k) {
                const float* row = &c2s[(rr4 + k) * ICP + icg * 4];
                float4 v0 = *(const float4*)(row);
                float4 v1 = *(const float4*)(row + 64);
                float4 v2 = *(const float4*)(row + 128);
                float wk = wq[k];
                acc[0][0] += wk * v0.x; acc[0][1] += wk * v0.y;
                acc[0][2] += wk * v0.z; acc[0][3] += wk * v0.w;
                acc[1][0] += wk * v1.x; acc[1][1] += wk * v1.y;
                acc[1][2] += wk * v1.z; acc[1][3] += wk * v1.w;
                acc[2][0] += wk * v2.x; acc[2][1] += wk * v2.y;
                acc[2][2] += wk * v2.z; acc[2][3] += wk * v2.w;
            }
        }
    }

    __syncthreads();
    // dump G tile (BT x 192) into LDS (reusing c2s), then contract with x_ext
    float* Gs = c2s;
#pragma unroll
    for (int p = 0; p < 3; ++p) {
        float4 v = make_float4(acc[p][0], acc[p][1], acc[p][2], acc[p][3]);
        *(float4*)&Gs[bl_local * ICP + icg * 4 + p * 64] = v;
    }
    __syncthreads();
    if (tid < BT * NC) {
        int bl = tid / NC, c = tid % NC;
        float y = 0.0f;
#pragma unroll
        for (int i = 0; i < 17; ++i)
            y += xe[bl * 17 + i] * Gs[bl * ICP + i * NC + c];
        out_y[(size_t)(bl0 + bl) * NC + c] = y;
    }
}

extern "C" void kernel_launch(void* const* d_in, const int* in_sizes, int n_in,
                              void* d_out, int out_size, void* d_ws, size_t ws_size,
                              hipStream_t stream) {
    const float* x        = (const float*)d_in[0];
    const float* centers  = (const float*)d_in[1];
    const float* widths   = (const float*)d_in[2];
    const float* cons     = (const float*)d_in[3];
    const int*   rule_idx = (const int*)d_in[4];

    float* out      = (float*)d_out;
    float* out_y    = out;                               // (4096,10)
    float* out_norm = out + (size_t)B * NC;              // (4096,1024)
    float* out_xext = out + (size_t)B * NC + (size_t)B * R; // (4096,17)

    unsigned* packed = (unsigned*)d_ws;                  // 1024 u32 = 4 KB scratch

    pack_rules<<<R / 256, 256, 0, stream>>>(rule_idx, packed);
    firing_kernel<<<B, 256, 0, stream>>>(x, centers, widths, packed, out_norm, out_xext);
    yhat_kernel<<<B / BT, 256, 0, stream>>>(out_norm, cons, x, out_y);
}

// Round 3
// 112.879 us; speedup vs baseline: 1.9513x; 1.9513x over previous
//
#include <hip/hip_runtime.h>

#define B 4096
#define D 16
#define R 1024
#define NC 10
#define IC 170       // 17*10
#define ICP 192      // padded leading dim for LDS C2 tile
#define RC 32        // rules per LDS chunk
#define BT 32        // batch rows per GEMM block
#define KSPLIT 8     // rule-range splits (grid = 128 M-tiles x 8)
#define RPB (R / KSPLIT)   // 128 rules per block
#define WSS 36       // padded wsh row stride (breaks 4-way bank alias; 36%4==0 keeps b128 align)

// ---------------- K0: pack rule_idx (16 dims x 2 bits) into one u32 per rule
__global__ void pack_rules(const int* __restrict__ rule_idx, unsigned* __restrict__ packed) {
    int r = blockIdx.x * 256 + threadIdx.x;
    unsigned bits = 0;
#pragma unroll
    for (int d = 0; d < D; ++d)
        bits |= (((unsigned)rule_idx[d * R + r]) & 3u) << (2 * d);
    packed[r] = bits;
}

// ---------------- K1: firing strengths + normalization + x_ext (+ zero y region)
__global__ __launch_bounds__(256) void firing_kernel(
    const float* __restrict__ x, const float* __restrict__ centers,
    const float* __restrict__ widths, const unsigned* __restrict__ packed,
    float* __restrict__ out_norm, float* __restrict__ out_xext,
    float* __restrict__ out_y)
{
    __shared__ float s_z[64];
    __shared__ float s_red[8];
    const int b = blockIdx.x, tid = threadIdx.x;

    // zero the y output (B*NC = 40960 = 160 blocks * 256 threads); runs before
    // yhat_kernel by stream order. Harness poisons d_out with 0xAA pre-launch.
    if (b < (B * NC) / 256) out_y[b * 256 + tid] = 0.0f;

    if (tid < 64) {
        int d = tid >> 2;
        float xv = x[b * D + d];
        float c  = centers[tid];
        float w  = widths[tid];
        float diff = xv - c;
        s_z[tid] = 1e-9f - diff * diff / (2.0f * w * w);
    }
    if (tid < 17) out_xext[b * 17 + tid] = (tid < 16) ? x[b * D + tid] : 1.0f;
    __syncthreads();

    float f[4];
    float lsum = 0.0f;
#pragma unroll
    for (int j = 0; j < 4; ++j) {
        int r = tid + 256 * j;
        unsigned bits = packed[r];
        float s = 0.0f;
#pragma unroll
        for (int d = 0; d < D; ++d)
            s += s_z[(d << 2) | ((bits >> (2 * d)) & 3u)];
        f[j] = __expf(s);
        lsum += f[j];
    }
#pragma unroll
    for (int off = 1; off < 64; off <<= 1) lsum += __shfl_xor(lsum, off, 64);
    const int lane = tid & 63, wid = tid >> 6;
    if (lane == 0) s_red[wid] = lsum;
    __syncthreads();
    if (tid == 0) {
        float tot = s_red[0] + s_red[1] + s_red[2] + s_red[3] + 1e-9f;
        s_red[4] = 1.0f / tot;
    }
    __syncthreads();
    const float inv = s_red[4];
#pragma unroll
    for (int j = 0; j < 4; ++j)
        out_norm[(size_t)b * R + tid + 256 * j] = f[j] * inv;
}

// ---------------- K2: partial GEMM over a 128-rule slice + in-block epilogue
// grid = 128 M-tiles x KSPLIT=8 -> 1024 blocks (4/CU), LDS ~31 KiB (4 blocks fit).
// Each thread: 2 batch rows x 12 ic cols -> 24 acc; C2 LDS reads amortized x2.
__global__ __launch_bounds__(256, 4) void yhat_kernel(
    const float* __restrict__ norm, const float* __restrict__ cons,
    const float* __restrict__ x, float* __restrict__ out_y)
{
    __shared__ float c2s[RC * ICP];    // 24 KiB (reused as G tile in epilogue: 32x192)
    __shared__ float wsh[BT * WSS];    // 4.5 KiB
    __shared__ float xe[BT * 17];

    const int tid = threadIdx.x;
    const int mt = blockIdx.x & 127;        // M tile
    const int ks = blockIdx.x >> 7;         // K split
    const int bl0 = mt * BT;
    const int r_base = ks * RPB;

    for (int t = tid; t < BT * 17; t += 256) {
        int bl = t / 17, i = t - bl * 17;
        xe[t] = (i < 16) ? x[(size_t)(bl0 + bl) * D + i] : 1.0f;
    }

    const int lane = tid & 63, wv = tid >> 6;
    const int icg = lane & 15;
    const int pp = wv * 4 + (lane >> 4);    // row-pair index 0..15
    const int row0 = pp * 2, row1 = row0 + 1;

    float acc[2][3][4];
#pragma unroll
    for (int r = 0; r < 2; ++r)
#pragma unroll
        for (int p = 0; p < 3; ++p)
#pragma unroll
            for (int q = 0; q < 4; ++q) acc[r][p][q] = 0.0f;

    for (int c0 = 0; c0 < RPB; c0 += RC) {
        __syncthreads();
        // stage C2 chunk (RC x 170) into padded rows
        for (int t = tid; t < RC * 85; t += 256) {
            int rr = t / 85;
            int j2 = (t - rr * 85) * 2;
            *(float2*)&c2s[rr * ICP + j2] =
                *(const float2*)(cons + (size_t)(r_base + c0 + rr) * IC + j2);
        }
        // stage norm_fs tile (BT x RC)
        for (int t = tid; t < BT * RC; t += 256) {
            int rw = t >> 5, rl = t & 31;
            wsh[rw * WSS + rl] = norm[(size_t)(bl0 + rw) * R + r_base + c0 + rl];
        }
        __syncthreads();

#pragma unroll
        for (int rr4 = 0; rr4 < RC; rr4 += 4) {
            float4 wA = *(const float4*)&wsh[row0 * WSS + rr4];
            float4 wB = *(const float4*)&wsh[row1 * WSS + rr4];
            float wa[4] = {wA.x, wA.y, wA.z, wA.w};
            float wb[4] = {wB.x, wB.y, wB.z, wB.w};
#pragma unroll
            for (int k = 0; k < 4; ++k) {
                const float* rowp = &c2s[(rr4 + k) * ICP + icg * 4];
                float4 v0 = *(const float4*)(rowp);
                float4 v1 = *(const float4*)(rowp + 64);
                float4 v2 = *(const float4*)(rowp + 128);
                float fa = wa[k], fb = wb[k];
                acc[0][0][0] += fa * v0.x; acc[0][0][1] += fa * v0.y;
                acc[0][0][2] += fa * v0.z; acc[0][0][3] += fa * v0.w;
                acc[0][1][0] += fa * v1.x; acc[0][1][1] += fa * v1.y;
                acc[0][1][2] += fa * v1.z; acc[0][1][3] += fa * v1.w;
                acc[0][2][0] += fa * v2.x; acc[0][2][1] += fa * v2.y;
                acc[0][2][2] += fa * v2.z; acc[0][2][3] += fa * v2.w;
                acc[1][0][0] += fb * v0.x; acc[1][0][1] += fb * v0.y;
                acc[1][0][2] += fb * v0.z; acc[1][0][3] += fb * v0.w;
                acc[1][1][0] += fb * v1.x; acc[1][1][1] += fb * v1.y;
                acc[1][1][2] += fb * v1.z; acc[1][1][3] += fb * v1.w;
                acc[1][2][0] += fb * v2.x; acc[1][2][1] += fb * v2.y;
                acc[1][2][2] += fb * v2.z; acc[1][2][3] += fb * v2.w;
            }
        }
    }

    __syncthreads();
    // dump partial G tile (BT x 192) into LDS (reuse c2s), contract with x_ext,
    // atomicAdd partial y (8-way contention across K-splits; y pre-zeroed by K1)
    float* Gs = c2s;
#pragma unroll
    for (int p = 0; p < 3; ++p) {
        *(float4*)&Gs[row0 * ICP + icg * 4 + p * 64] =
            make_float4(acc[0][p][0], acc[0][p][1], acc[0][p][2], acc[0][p][3]);
        *(float4*)&Gs[row1 * ICP + icg * 4 + p * 64] =
            make_float4(acc[1][p][0], acc[1][p][1], acc[1][p][2], acc[1][p][3]);
    }
    __syncthreads();
    for (int t = tid; t < BT * NC; t += 256) {
        int bl = t / NC, c = t - bl * NC;
        float y = 0.0f;
#pragma unroll
        for (int i = 0; i < 17; ++i)
            y += xe[bl * 17 + i] * Gs[bl * ICP + i * NC + c];
        atomicAdd(&out_y[(size_t)(bl0 + bl) * NC + c], y);
    }
}

extern "C" void kernel_launch(void* const* d_in, const int* in_sizes, int n_in,
                              void* d_out, int out_size, void* d_ws, size_t ws_size,
                              hipStream_t stream) {
    const float* x        = (const float*)d_in[0];
    const float* centers  = (const float*)d_in[1];
    const float* widths   = (const float*)d_in[2];
    const float* cons     = (const float*)d_in[3];
    const int*   rule_idx = (const int*)d_in[4];

    float* out      = (float*)d_out;
    float* out_y    = out;                                  // (4096,10)
    float* out_norm = out + (size_t)B * NC;                 // (4096,1024)
    float* out_xext = out + (size_t)B * NC + (size_t)B * R; // (4096,17)

    unsigned* packed = (unsigned*)d_ws;                     // 4 KB scratch

    pack_rules<<<R / 256, 256, 0, stream>>>(rule_idx, packed);
    firing_kernel<<<B, 256, 0, stream>>>(x, centers, widths, packed,
                                         out_norm, out_xext, out_y);
    yhat_kernel<<<(B / BT) * KSPLIT, 256, 0, stream>>>(out_norm, cons, x, out_y);
}

// Round 4
// 94.175 us; speedup vs baseline: 2.3388x; 1.1986x over previous
//
#include <hip/hip_runtime.h>

#define B 4096
#define D 16
#define R 1024
#define NC 10
#define IC 170
#define NT 11          // n-tiles of 16 -> 176 padded cols
#define NP 176
#define KC 64          // k per LDS staging chunk
#define KSPLIT 4
#define RPB (R / KSPLIT)   // 256 rules per block
#define BT 16          // batch rows per block
#define BSTR 72        // padded k-stride (bf16) for Bs/As: breaks 16-way b128 bank conflict
#define GSP 192        // Gs (epilogue) padded row stride

typedef __attribute__((ext_vector_type(8))) short short8;
typedef __attribute__((ext_vector_type(4))) float f32x4;

__device__ __forceinline__ unsigned short f2bf(float f) {
    unsigned u = __float_as_uint(f);
    return (unsigned short)((u + 0x7fffu + ((u >> 16) & 1u)) >> 16);  // RNE
}

// ---------------- K0: pack rule_idx (16 dims x 2 bits). Byte q of the packed
// word is exactly the 8-bit quad-table index for dims 4q..4q+3.
__global__ void pack_rules(const int* __restrict__ rule_idx, unsigned* __restrict__ packed) {
    int r = blockIdx.x * 256 + threadIdx.x;
    unsigned bits = 0;
#pragma unroll
    for (int d = 0; d < D; ++d)
        bits |= (((unsigned)rule_idx[d * R + r]) & 3u) << (2 * d);
    packed[r] = bits;
}

// ---------------- K0b: consequents fp32 [1024][170] -> Bsw bf16 [176][1024]
// (column-major per output col: MFMA B-fragment reads become contiguous 16B)
__global__ __launch_bounds__(256) void convert_b(const float* __restrict__ cons,
                                                 unsigned short* __restrict__ Bsw) {
    int t = blockIdx.x * 256 + threadIdx.x;   // t < 176*1024
    int row = t >> 10;                        // col index 0..175
    int k   = t & 1023;
    float v = (row < IC) ? cons[(size_t)k * IC + row] : 0.0f;
    Bsw[t] = f2bf(v);
}

// ---------------- K1: firing via quad tables (4 LDS gathers/rule instead of 16)
__global__ __launch_bounds__(256) void firing_kernel(
    const float* __restrict__ x, const float* __restrict__ centers,
    const float* __restrict__ widths, const unsigned* __restrict__ packed,
    float* __restrict__ out_norm, float* __restrict__ out_xext,
    float* __restrict__ out_y)
{
    __shared__ float s_z[64];
    __shared__ float s_z2[8][16];
    __shared__ float s_z4[4 * 256];
    __shared__ float s_red[8];
    const int b = blockIdx.x, tid = threadIdx.x;

    // zero y output (runs before yhat by stream order)
    if (b < (B * NC) / 256) out_y[b * 256 + tid] = 0.0f;

    if (tid < 64) {
        int d = tid >> 2;
        float xv = x[b * D + d];
        float c = centers[tid], w = widths[tid];
        float diff = xv - c;
        s_z[tid] = 1e-9f - diff * diff / (2.0f * w * w);
    }
    if (tid < 17) out_xext[b * 17 + tid] = (tid < 16) ? x[b * D + tid] : 1.0f;
    __syncthreads();
    if (tid < 128) {  // pair tables: pair p = dims (2p, 2p+1)
        int p = tid >> 4, i = tid & 15;
        s_z2[p][i] = s_z[p * 8 + (i & 3)] + s_z[p * 8 + 4 + ((i >> 2) & 3)];
    }
    __syncthreads();
#pragma unroll
    for (int q = 0; q < 4; ++q)   // quad q = pairs (2q, 2q+1)
        s_z4[q * 256 + tid] = s_z2[2 * q][tid & 15] + s_z2[2 * q + 1][(tid >> 4) & 15];
    __syncthreads();

    float f[4], lsum = 0.0f;
#pragma unroll
    for (int j = 0; j < 4; ++j) {
        unsigned w = packed[tid + 256 * j];
        float s = s_z4[w & 255] + s_z4[256 + ((w >> 8) & 255)]
                + s_z4[512 + ((w >> 16) & 255)] + s_z4[768 + (w >> 24)];
        f[j] = __expf(s);
        lsum += f[j];
    }
#pragma unroll
    for (int off = 1; off < 64; off <<= 1) lsum += __shfl_xor(lsum, off, 64);
    const int lane = tid & 63, wid = tid >> 6;
    if (lane == 0) s_red[wid] = lsum;
    __syncthreads();
    if (tid == 0) {
        float tot = s_red[0] + s_red[1] + s_red[2] + s_red[3] + 1e-9f;
        s_red[4] = 1.0f / tot;
    }
    __syncthreads();
    const float inv = s_red[4];
#pragma unroll
    for (int j = 0; j < 4; ++j)
        out_norm[(size_t)b * R + tid + 256 * j] = f[j] * inv;
}

// ---------------- K2: MFMA GEMM. Block = 16 rows x 176 cols, K-slice of 256
// rules (KSPLIT=4). 4 waves split the 11 n-tiles 3/3/3/2. A (norm fp32) is
// converted to bf16 during LDS staging. Epilogue contracts with x_ext in-LDS
// and atomicAdds partial y (y pre-zeroed by K1).
__global__ __launch_bounds__(256, 4) void yhat_kernel(
    const float* __restrict__ norm, const unsigned short* __restrict__ Bsw,
    const float* __restrict__ x, float* __restrict__ out_y)
{
    __shared__ unsigned short Bs[NT * 16 * BSTR];   // 25344 B (reused as Gs)
    __shared__ unsigned short As[BT * BSTR];        // 2304 B
    __shared__ float xe[BT * 17];

    const int tid = threadIdx.x;
    const int mt = blockIdx.x & 255;
    const int ks = blockIdx.x >> 8;
    const int bl0 = mt * BT;
    const int r_base = ks * RPB;

    for (int t = tid; t < BT * 17; t += 256) {      // 272 > 256: strided loop!
        int bl = t / 17, i = t - bl * 17;
        xe[t] = (i < 16) ? x[(size_t)(bl0 + bl) * D + i] : 1.0f;
    }

    const int lane = tid & 63, wv = tid >> 6;
    const int m_ = lane & 15, q_ = lane >> 4;
    const int nt0 = wv * 3;
    const int ntn = (wv == 3) ? 2 : 3;

    f32x4 acc[3];
    const f32x4 zf = {0.f, 0.f, 0.f, 0.f};
    acc[0] = zf; acc[1] = zf; acc[2] = zf;

    for (int c0 = 0; c0 < RPB; c0 += KC) {
        const int kabs = r_base + c0;
        __syncthreads();
        // stage B chunk: 176 cols x 64 k (128 B each) from pre-swizzled Bsw
        for (int t = tid; t < NP * 8; t += 256) {
            int row = t >> 3, seg = t & 7;
            *(short8*)&Bs[row * BSTR + seg * 8] =
                *(const short8*)&Bsw[row * R + kabs + seg * 8];
        }
        // stage A: 16 rows x 64 k, fp32 -> bf16 (exactly 256 float4 loads)
        {
            int row = tid >> 4, c4 = tid & 15;
            float4 v = *(const float4*)&norm[(size_t)(bl0 + row) * R + kabs + c4 * 4];
            ushort4 o;
            o.x = f2bf(v.x); o.y = f2bf(v.y); o.z = f2bf(v.z); o.w = f2bf(v.w);
            *(ushort4*)&As[row * BSTR + c4 * 4] = o;
        }
        __syncthreads();
#pragma unroll
        for (int kh = 0; kh < 2; ++kh) {
            short8 a = *(const short8*)&As[m_ * BSTR + kh * 32 + q_ * 8];
#pragma unroll
            for (int j = 0; j < 3; ++j) {
                if (j < ntn) {
                    int nt = nt0 + j;
                    short8 bfrag = *(const short8*)&Bs[(nt * 16 + m_) * BSTR + kh * 32 + q_ * 8];
                    acc[j] = __builtin_amdgcn_mfma_f32_16x16x32_bf16(a, bfrag, acc[j], 0, 0, 0);
                }
            }
        }
    }

    __syncthreads();
    float* Gs = (float*)Bs;    // 16 x 192 fp32 = 12288 B, fits in Bs
#pragma unroll
    for (int j = 0; j < 3; ++j) {
        if (j < ntn) {
            int nt = nt0 + j;
#pragma unroll
            for (int r = 0; r < 4; ++r)
                Gs[(q_ * 4 + r) * GSP + nt * 16 + m_] = acc[j][r];   // C/D: col=lane&15, row=quad*4+reg
        }
    }
    __syncthreads();
    if (tid < BT * NC) {
        int bl = tid / NC, c = tid - bl * NC;
        float y = 0.0f;
#pragma unroll
        for (int i = 0; i < 17; ++i)
            y += xe[bl * 17 + i] * Gs[bl * GSP + i * NC + c];
        atomicAdd(&out_y[(size_t)(bl0 + bl) * NC + c], y);
    }
}

extern "C" void kernel_launch(void* const* d_in, const int* in_sizes, int n_in,
                              void* d_out, int out_size, void* d_ws, size_t ws_size,
                              hipStream_t stream) {
    const float* x        = (const float*)d_in[0];
    const float* centers  = (const float*)d_in[1];
    const float* widths   = (const float*)d_in[2];
    const float* cons     = (const float*)d_in[3];
    const int*   rule_idx = (const int*)d_in[4];

    float* out      = (float*)d_out;
    float* out_y    = out;                                  // (4096,10)
    float* out_norm = out + (size_t)B * NC;                 // (4096,1024)
    float* out_xext = out + (size_t)B * NC + (size_t)B * R; // (4096,17)

    unsigned* packed     = (unsigned*)d_ws;                          // 4 KB
    unsigned short* Bsw  = (unsigned short*)((char*)d_ws + 4096);    // 352 KB

    pack_rules<<<R / 256, 256, 0, stream>>>(rule_idx, packed);
    convert_b<<<(NP * R) / 256, 256, 0, stream>>>(cons, Bsw);
    firing_kernel<<<B, 256, 0, stream>>>(x, centers, widths, packed,
                                         out_norm, out_xext, out_y);
    yhat_kernel<<<(B / BT) * KSPLIT, 256, 0, stream>>>(out_norm, Bsw, x, out_y);
}